// Round 8
// baseline (361.461 us; speedup 1.0000x reference)
//
#include <hip/hip_runtime.h>

// 6-level 2D DB4 wavelet (forward -> soft threshold -> inverse), N=4096 fp32.
// R10: XCD-LOCAL middle core. Evidence across R2-R9: each dispatch edge costs
// ~13-16us (AQL barrier-packet L2 writeback-invalidate across 8 non-coherent
// XCDs); in-kernel cross-XCD sync pays the same (R8) or worse (R4/R7). The
// loophole: run ALL middle levels (2..5 fwd + thr + inv 5..2) on ONE XCD --
// producer->consumer flows through that XCD's own L2 with NO fences, NO wbl2,
// NO dispatch edges. Blocks read HW_REG_XCC_ID (HW-verified gfx950, m09);
// non-XCD0 blocks exit. Phase gates = plain agent atomics on done-counters
// (work-based, deadlock-free under any residency). 5 dispatches total:
//   fwd0 | fwd1(+counter reset) | core_mid(XCD0) | inv1 | inv0
// Tile bodies identical to R9 (verified): fwd 32x32-out direct-global stage A,
// inv 64x64-out direct-global stage A, <=64 VGPR, 8 blocks/CU.
//
// d_out layout: [0 .. 16777216) reconstruction, [16777216 .. 33554432) flat coeffs.
// Flat per level: row i = [hh_i | hl_i | lh_i], row stride 3*sc; final thr(approx)
// (64x64) at the tail.
// ws layout (floats): A1..A6 [0 .. 5591040) | P0 (4194304) | P1 (4194304) |
// counter region (512 uints) at float offset 14680064.
//   ticket[p] = bar[p*32], done[p] = bar[256 + p*32], p = 0..7.

__device__ __forceinline__ float thrf(float t, float alpha, float bp, float bm) {
    float s1 = 1.0f / (1.0f + __expf(-alpha * (t - bp)));
    float s2 = 1.0f / (1.0f + __expf( alpha * (t + bm)));
    return t * (s1 + s2);
}

__device__ __forceinline__ void load_h(const float* __restrict__ filt,
                                       float (&h)[8]) {
#pragma unroll
    for (int k = 0; k < 8; ++k) h[k] = filt[k];
}

struct SMemF { float Ds[70][36]; float As[70][36]; };  // 20160 B
struct SMemI { float Hs[64][36]; float Ls[64][36]; };  // 18432 B
union SMem { SMemF f; SMemI i; };

// Forward tile: X (s x s) -> thresholded hh|hl|lh into flat (stride 3*sh)
// + ll into All (stride sh; thresholded too when thr_ll). (R9-verified.)
__device__ __forceinline__ void fwd_tile(
    SMemF& sm, const float* __restrict__ X, int s, int sh,
    float* __restrict__ flat, float* __restrict__ All, bool thr_ll,
    const float (&h)[8], const float (&g)[8],
    float alpha, float bp, float bm, int i0, int j0, int tid) {
    const int smk = s - 1;
    // stage A: row filter straight from global (4 aligned float4 per window).
    for (int idx = tid; idx < 70 * 8; idx += 256) {
        int rr = idx >> 3, q = idx & 7;
        int gr = (2 * i0 - 7 + rr) & smk;
        const float* xrow = X + (size_t)gr * s;
        int cbase = 2 * j0 - 8 + 8 * q;
        float wv[16];
#pragma unroll
        for (int m = 0; m < 4; ++m) {
            float4 t = *(const float4*)&xrow[(cbase + 4 * m) & smk];
            wv[4 * m + 0] = t.x; wv[4 * m + 1] = t.y;
            wv[4 * m + 2] = t.z; wv[4 * m + 3] = t.w;
        }
        float d[4], a[4];
#pragma unroll
        for (int e = 0; e < 4; ++e) {
            float dd = 0.f, aa = 0.f;
#pragma unroll
            for (int u = 0; u < 8; ++u) {
                float v = wv[2 * e + 1 + u];
                aa += h[7 - u] * v;
                dd += (u & 1) ? h[u] * v : -h[u] * v;
            }
            d[e] = dd; a[e] = aa;
        }
        *(float4*)&sm.Ds[rr][4 * q] = make_float4(d[0], d[1], d[2], d[3]);
        *(float4*)&sm.As[rr][4 * q] = make_float4(a[0], a[1], a[2], a[3]);
    }
    __syncthreads();
    // stage B: col filter from LDS; D-pass then A-pass (register-lean).
    const int j = tid & 31, iq = tid >> 5;
    {
        float Dw[14];
#pragma unroll
        for (int t = 0; t < 14; ++t) Dw[t] = sm.Ds[8 * iq + t][j];
#pragma unroll
        for (int e = 0; e < 4; ++e) {
            float hh = 0.f, hl = 0.f;
#pragma unroll
            for (int u = 0; u < 8; ++u) {
                float dv = Dw[2 * e + u];
                hl += g[7 - u] * dv;
                hh += (u & 1) ? g[u] * dv : -g[u] * dv;
            }
            int row = i0 + 4 * iq + e;
            size_t ro = (size_t)row * (3 * sh) + (j0 + j);
            flat[ro]      = thrf(hh, alpha, bp, bm);
            flat[ro + sh] = thrf(hl, alpha, bp, bm);
        }
    }
    {
        float Aw[14];
#pragma unroll
        for (int t = 0; t < 14; ++t) Aw[t] = sm.As[8 * iq + t][j];
#pragma unroll
        for (int e = 0; e < 4; ++e) {
            float lh = 0.f, ll = 0.f;
#pragma unroll
            for (int u = 0; u < 8; ++u) {
                float av = Aw[2 * e + u];
                ll += g[7 - u] * av;
                lh += (u & 1) ? g[u] * av : -g[u] * av;
            }
            int row = i0 + 4 * iq + e;
            size_t ro = (size_t)row * (3 * sh) + (j0 + j);
            flat[ro + 2 * sh] = thrf(lh, alpha, bp, bm);
            All[(size_t)row * sh + (j0 + j)] =
                thr_ll ? thrf(ll, alpha, bp, bm) : ll;
        }
    }
}

// Inverse tile: hh|hl|lh (stride 3*sc) + a (stride astride) -> 64x64 out tile.
// (R9-verified.)
__device__ __forceinline__ void inv_tile(
    SMemI& sm, const float* __restrict__ flatl, const float* __restrict__ a,
    int astride, int sc, float* __restrict__ outp, int ostride,
    const float (&h)[8], const float (&g)[8],
    int i0, int m0, int tid) {
    const int mm = sc - 1;
    const int r0 = i0 >> 1, c0 = m0 >> 1;
    const int ds = 3 * sc;
    // stage A: col inverse straight from global (coalesced rows).
    for (int idx = tid; idx < 16 * 36; idx += 256) {
        int q = idx / 36, jj = idx - q * 36;
        int gc = (c0 + jj) & mm;
        {   // H from (hh, hl)
            float hv[6], lv[6];
#pragma unroll
            for (int d = 0; d < 6; ++d) {
                size_t o = (size_t)((r0 + 2 * q + d) & mm) * ds + gc;
                hv[d] = flatl[o];
                lv[d] = flatl[o + sc];
            }
            float H0 = 0.f, H1 = 0.f, H2 = 0.f, H3 = 0.f;
#pragma unroll
            for (int t = 0; t < 4; ++t) {
                float we = g[7 - 2 * t], wo = -g[6 - 2 * t];
                float he = g[2 * t],     ho = g[2 * t + 1];
                H0 += we * hv[t]     + he * lv[t];
                H1 += wo * hv[t + 1] + ho * lv[t + 1];
                H2 += we * hv[t + 1] + he * lv[t + 1];
                H3 += wo * hv[t + 2] + ho * lv[t + 2];
            }
            sm.Hs[4 * q + 0][jj] = H0; sm.Hs[4 * q + 1][jj] = H1;
            sm.Hs[4 * q + 2][jj] = H2; sm.Hs[4 * q + 3][jj] = H3;
        }
        {   // L from (lh, a)
            float gv[6], av[6];
#pragma unroll
            for (int d = 0; d < 6; ++d) {
                int grr = (r0 + 2 * q + d) & mm;
                gv[d] = flatl[(size_t)grr * ds + 2 * sc + gc];
                av[d] = a[(size_t)grr * astride + gc];
            }
            float L0 = 0.f, L1 = 0.f, L2 = 0.f, L3 = 0.f;
#pragma unroll
            for (int t = 0; t < 4; ++t) {
                float we = g[7 - 2 * t], wo = -g[6 - 2 * t];
                float he = g[2 * t],     ho = g[2 * t + 1];
                L0 += we * gv[t]     + he * av[t];
                L1 += wo * gv[t + 1] + ho * av[t + 1];
                L2 += we * gv[t + 1] + he * av[t + 1];
                L3 += wo * gv[t + 2] + ho * av[t + 2];
            }
            sm.Ls[4 * q + 0][jj] = L0; sm.Ls[4 * q + 1][jj] = L1;
            sm.Ls[4 * q + 2][jj] = L2; sm.Ls[4 * q + 3][jj] = L3;
        }
    }
    __syncthreads();
    // stage B: row inverse from LDS, float4 store.
    for (int idx = tid; idx < 64 * 16; idx += 256) {
        int i = idx >> 4, p = idx & 15;
        const float2* hp = (const float2*)&sm.Hs[i][2 * p];
        const float2* lp = (const float2*)&sm.Ls[i][2 * p];
        float2 hA = hp[0], hB = hp[1], hC = hp[2];
        float2 lA = lp[0], lB = lp[1], lC = lp[2];
        float Hw[6] = {hA.x, hA.y, hB.x, hB.y, hC.x, hC.y};
        float Lw[6] = {lA.x, lA.y, lB.x, lB.y, lC.x, lC.y};
        float o0 = 0.f, o1 = 0.f, o2 = 0.f, o3 = 0.f;
#pragma unroll
        for (int t = 0; t < 4; ++t) {
            float we = h[7 - 2 * t], wo = -h[6 - 2 * t];
            float he = h[2 * t],     ho = h[2 * t + 1];
            o0 += we * Hw[t]     + he * Lw[t];
            o1 += wo * Hw[t + 1] + ho * Lw[t + 1];
            o2 += we * Hw[t + 1] + he * Lw[t + 1];
            o3 += wo * Hw[t + 2] + ho * Lw[t + 2];
        }
        *(float4*)&outp[(size_t)(i0 + i) * ostride + (m0 + 4 * p)] =
            make_float4(o0, o1, o2, o3);
    }
}

__global__ __launch_bounds__(256, 8) void fwd_fused(
    const float* __restrict__ X, int s, int sh,
    float* __restrict__ flat, float* __restrict__ All, int thr_ll,
    const float* __restrict__ filt_row, const float* __restrict__ filt_col,
    const float* __restrict__ ap, const float* __restrict__ bpp,
    const float* __restrict__ bmp, unsigned* bar_reset) {
    __shared__ SMemF smem;
    float h[8], g[8];
    load_h(filt_row, h);
    load_h(filt_col, g);
    const float alpha = *ap, bp = *bpp, bm = *bmp;
    fwd_tile(smem, X, s, sh, flat, All, thr_ll != 0, h, g,
             alpha, bp, bm, blockIdx.y * 32, blockIdx.x * 32, threadIdx.x);
    // zero the 16 counter slots (tickets + dones); this kernel strictly
    // precedes core_mid in stream order (edge flush makes it visible).
    if (bar_reset && blockIdx.x == 0 && blockIdx.y == 0 && threadIdx.x < 16)
        bar_reset[threadIdx.x * 32] = 0u;
}

__global__ __launch_bounds__(256, 8) void inv_fused(
    const float* __restrict__ flatl, const float* __restrict__ a, int astride,
    int sc, float* __restrict__ outp, int ostride,
    const float* __restrict__ filt_col, const float* __restrict__ filt_row) {
    __shared__ SMemI smem;
    float h[8], g[8];
    load_h(filt_row, h);
    load_h(filt_col, g);
    inv_tile(smem, flatl, a, astride, sc, outp, ostride, h, g,
             blockIdx.y * 64, blockIdx.x * 64, threadIdx.x);
}

// ---- XCD0-only middle core: fwd 2..5 (+thr) then inv 5..2. ----
// Phases p=0..7 -> lev {2,3,4,5,5,4,3,2}. All workers on XCD0 => all data
// coherent through XCD0's L2; NO fences needed. Gates are agent atomics.
__global__ __launch_bounds__(256, 8) void core_mid(
    const float* __restrict__ scal, const float* __restrict__ ap,
    const float* __restrict__ bpp, const float* __restrict__ bmp,
    float* __restrict__ out, float* __restrict__ ws, unsigned* __restrict__ bar) {
    unsigned xcc;
    asm volatile("s_getreg_b32 %0, hwreg(HW_REG_XCC_ID, 0, 32)" : "=s"(xcc));
    if (xcc != 0u) return;  // only XCD0 blocks participate
    __shared__ SMem smem;
    __shared__ int curt;
    const int tid = threadIdx.x;
    const float alpha = *ap, bp = *bpp, bm = *bmp;
    const int N = 4096;
    float* flat = out + 16777216;
    const size_t Aoff[7]    = {0, 0, 4194304, 5242880, 5505024, 5570560, 5586944};
    const size_t flatOff[6] = {0, 12582912, 15728640, 16515072, 16711680, 16760832};
    const size_t finalOff = 16773120;
    float* P0 = ws + 5591040;
    float* P1 = ws + 5591040 + 4194304;

    const float* a_in = flat + finalOff;
    int prevNp = 0;

    for (int p = 0; p < 8; ++p) {
        const int lev = (p < 4) ? (2 + p) : (9 - p);   // 2,3,4,5,5,4,3,2
        const int nt  = N >> (lev + 6);                // tiles/side (fwd & inv)
        const int Np  = nt * nt;

        // gate: wait until ALL tiles of phase p-1 are done (work-based).
        if (p > 0) {
            if (tid == 0) {
                while (__hip_atomic_load(&bar[256 + (p - 1) * 32], __ATOMIC_RELAXED,
                                         __HIP_MEMORY_SCOPE_AGENT) < (unsigned)prevNp) {
                    __builtin_amdgcn_s_sleep(1);
                }
            }
            __syncthreads();   // no acquire fence: producers share our L2
        }

        float h[8], g[8];
        load_h(scal + lev * 8, h);
        load_h(scal + (lev + 1) * 8, g);
        unsigned cnt = 0;

        if (p < 4) {
            const int s = N >> lev, sh = s >> 1;
            const float* src = ws + Aoff[lev];
            float* All = (lev < 5) ? (ws + Aoff[lev + 1]) : (flat + finalOff);
            for (;;) {
                __syncthreads();
                if (tid == 0) curt = (int)atomicAdd(&bar[p * 32], 1u);
                __syncthreads();
                const int t = curt;
                if (t >= Np) break;
                fwd_tile(smem.f, src, s, sh, flat + flatOff[lev], All, lev == 5,
                         h, g, alpha, bp, bm, (t / nt) * 32, (t % nt) * 32, tid);
                ++cnt;
            }
        } else {
            const int sc = N >> (lev + 1), r = 2 * sc;
            float* outp = (lev & 1) ? P1 : P0;
            for (;;) {
                __syncthreads();
                if (tid == 0) curt = (int)atomicAdd(&bar[p * 32], 1u);
                __syncthreads();
                const int t = curt;
                if (t >= Np) break;
                inv_tile(smem.i, flat + flatOff[lev], a_in, sc, sc, outp, r,
                         h, g, (t / nt) * 64, (t % nt) * 64, tid);
                ++cnt;
            }
            a_in = outp;  // uniform across block
        }

        // signal: __syncthreads drains vmcnt(0) per wave (stores in our L2),
        // then publish count. No fence (XCD-local visibility).
        __syncthreads();
        if (tid == 0 && cnt) atomicAdd(&bar[256 + p * 32], cnt);
        prevNp = Np;
    }
}

extern "C" void kernel_launch(void* const* d_in, const int* in_sizes, int n_in,
                              void* d_out, int out_size, void* d_ws, size_t ws_size,
                              hipStream_t stream) {
    const float* x    = (const float*)d_in[0];
    const float* scal = (const float*)d_in[1];  // 12 x 8
    const float* ap   = (const float*)d_in[2];
    const float* bp   = (const float*)d_in[3];
    const float* bm   = (const float*)d_in[4];
    float* out = (float*)d_out;
    float* ws  = (float*)d_ws;

    float* recon = out;
    float* flat  = out + 16777216;
    static const size_t Aoff[7]    = {0, 0, 4194304, 5242880, 5505024, 5570560, 5586944};
    static const size_t flatOff[6] = {0, 12582912, 15728640, 16515072, 16711680, 16760832};
    float* P0 = ws + 5591040;
    float* P1 = ws + 5591040 + 4194304;
    unsigned* bar = (unsigned*)(ws + 14680064);  // past all live ws data

    dim3 blk(256);

    // fwd level 0: x (4096) -> flat0 + A1
    fwd_fused<<<dim3(64, 64), blk, 0, stream>>>(
        x, 4096, 2048, flat + flatOff[0], ws + Aoff[1], 0,
        scal, scal + 8, ap, bp, bm, (unsigned*)nullptr);

    // fwd level 1: A1 -> flat1 + A2   (+ counter reset for core_mid)
    fwd_fused<<<dim3(32, 32), blk, 0, stream>>>(
        ws + Aoff[1], 2048, 1024, flat + flatOff[1], ws + Aoff[2], 0,
        scal + 8, scal + 16, ap, bp, bm, bar);

    // middle core on XCD0: fwd 2..5 (+thr) and inv 5..2  (ends with P0 = inv2 out)
    core_mid<<<dim3(2048), blk, 0, stream>>>(scal, ap, bp, bm, out, ws, bar);

    // inv level 1: flat1 + P0 -> P1
    inv_fused<<<dim3(32, 32), blk, 0, stream>>>(
        flat + flatOff[1], P0, 1024, 1024, P1, 2048, scal + 16, scal + 8);

    // inv level 0: flat0 + P1 -> recon
    inv_fused<<<dim3(64, 64), blk, 0, stream>>>(
        flat + flatOff[0], P1, 2048, 2048, recon, 4096, scal + 8, scal);
}